// Round 5
// baseline (569.494 us; speedup 1.0000x reference)
//
#include <hip/hip_runtime.h>
#include <math.h>

#define EPS 1e-8f
#define FMAXV 3.402823466e38f

// Preprocess: sp4[j] = (-2x, -2y, -2z, s2), s2 = (x*x + y*y) + z*z in strict
// fp32 no-FMA (mirrors np.sum(s*s, -1): separate multiply op then sequential
// sum). The -2 scale is a power of two => exact, commutes with all rounding.
__global__ void knn_preproc(const float* __restrict__ sp, float4* __restrict__ sp4, int N) {
    int j = blockIdx.x * blockDim.x + threadIdx.x;
    if (j < N) {
        float x = sp[3 * j + 0], y = sp[3 * j + 1], z = sp[3 * j + 2];
        float s2 = __fadd_rn(__fadd_rn(__fmul_rn(x, x), __fmul_rn(y, y)), __fmul_rn(z, z));
        sp4[j] = make_float4(-2.f * x, -2.f * y, -2.f * z, s2);
    }
}

__device__ __forceinline__ void insert3(float d, int j,
                                        float& d0, float& d1, float& d2,
                                        int& i0, int& i1, int& i2) {
    if (d < d2) {
        if (d < d1) {
            d2 = d1; i2 = i1;
            if (d < d0) { d1 = d0; i1 = i0; d0 = d; i0 = j; }
            else        { d1 = d;  i1 = j; }
        } else { d2 = d; i2 = j; }
    }
}

// One block = 64 targets (lane = target), 4 waves scan disjoint N/4 chunks
// (wave-uniform index -> scalar loads), merge partial top-3s in LDS, IDW
// weights, coalesced float4 feature interpolation.
//
// Distance arithmetic mirrors the BLAS-sgemm expanded form BIT-EXACTLY:
//   cross = fma(tz*sz, fma(ty*sy, rn(tx*sx)))   (FMA chain, k ascending,
//                                                acc init 0 — BLAS microkernel)
//   d     = rn(rn(t2 - 2*cross) + s2)           (elementwise, no FMA)
// with t2, s2 from separate ops: (xx+yy)+zz, no FMA.
// R3 refuted the no-FMA-cross variant bitwise; R4's f64 re-rank refuted an
// f64 reference. The reference's ~1e-6 cancellation noise flips near-tie
// rank-3/4 rows, so we must match its rounding realization, not beat it.
__global__ __launch_bounds__(256) void knn_kernel(
    const float4* __restrict__ sp4, const float* __restrict__ feat,
    const float* __restrict__ tp, float* __restrict__ out,
    int N, int M, int C) {
    __shared__ float s_d[64][4][3];
    __shared__ int   s_i[64][4][3];
    __shared__ float s_w[64][3];
    __shared__ int   s_j[64][3];

    const int tid  = threadIdx.x;
    const int lane = tid & 63;
    const int wave = __builtin_amdgcn_readfirstlane(tid >> 6);
    const int mbase = blockIdx.x * 64;
    const int m = mbase + lane;

    float tx = 0.f, ty = 0.f, tz = 0.f;
    if (m < M) { tx = tp[3 * m + 0]; ty = tp[3 * m + 1]; tz = tp[3 * m + 2]; }
    // t2 = (tx*tx + ty*ty) + tz*tz, strict no-FMA (separate-op numpy sum)
    const float t2 = __fadd_rn(__fadd_rn(__fmul_rn(tx, tx), __fmul_rn(ty, ty)),
                               __fmul_rn(tz, tz));

    float d0 = FMAXV, d1 = FMAXV, d2 = FMAXV;
    int   i0 = 0,     i1 = 0,     i2 = 0;

    const int chunk = (N + 3) >> 2;
    const int jbeg = wave * chunk;
    const int jend = min(jbeg + chunk, N);

    #pragma unroll 4
    for (int j = jbeg; j < jend; ++j) {
        float4 p = sp4[j];  // wave-uniform index -> scalar load
        // a = -2*cross via exact-scaled FMA chain (k ascending, acc from 0):
        //   fma(-2sz,tz, fma(-2sy,ty, rn(-2sx*tx))) == -2*fma(sz,tz, fma(sy,ty, rn(sx*tx)))
        float a = fmaf(p.z, tz, fmaf(p.y, ty, __fmul_rn(p.x, tx)));
        // d = rn(rn(t2 - 2*cross) + s2); rn(2*cross)=2*cross exact.
        float d = __fadd_rn(__fadd_rn(t2, a), p.w);
        insert3(d, j, d0, d1, d2, i0, i1, i2);
    }

    s_d[lane][wave][0] = d0; s_d[lane][wave][1] = d1; s_d[lane][wave][2] = d2;
    s_i[lane][wave][0] = i0; s_i[lane][wave][1] = i1; s_i[lane][wave][2] = i2;
    __syncthreads();

    if (wave == 0) {
        float b0 = FMAXV, b1 = FMAXV, b2 = FMAXV;
        int   j0 = 0,     j1 = 0,     j2 = 0;
        // Merge in wave order (ascending source index) with strict '<' so
        // equal scores keep the smallest index (top_k tie-break).
        #pragma unroll
        for (int w = 0; w < 4; ++w)
            #pragma unroll
            for (int k = 0; k < 3; ++k)
                insert3(s_d[lane][w][k], s_i[lane][w][k], b0, b1, b2, j0, j1, j2);
        // Mirror: w = 1/(d+eps); w /= (w0+w1)+w2   (all fp32, rn)
        float w0 = __fdiv_rn(1.f, __fadd_rn(b0, EPS));
        float w1 = __fdiv_rn(1.f, __fadd_rn(b1, EPS));
        float w2 = __fdiv_rn(1.f, __fadd_rn(b2, EPS));
        float sum = __fadd_rn(__fadd_rn(w0, w1), w2);
        s_w[lane][0] = __fdiv_rn(w0, sum);
        s_w[lane][1] = __fdiv_rn(w1, sum);
        s_w[lane][2] = __fdiv_rn(w2, sum);
        s_j[lane][0] = j0; s_j[lane][1] = j1; s_j[lane][2] = j2;
    }
    __syncthreads();

    // Interpolation: thread -> (target tm, quarter q), C/4 contiguous
    // channels per thread with float4 loads/stores.
    const int tm = tid >> 2;
    const int q  = tid & 3;
    const int gm = mbase + tm;
    if (gm < M) {
        const int nv = C >> 4;          // float4s per quarter
        const float w0 = s_w[tm][0], w1 = s_w[tm][1], w2 = s_w[tm][2];
        const float4* f0 = (const float4*)(feat + (size_t)s_j[tm][0] * C) + q * nv;
        const float4* f1 = (const float4*)(feat + (size_t)s_j[tm][1] * C) + q * nv;
        const float4* f2 = (const float4*)(feat + (size_t)s_j[tm][2] * C) + q * nv;
        float4* o = (float4*)(out + (size_t)gm * C) + q * nv;
        for (int r = 0; r < nv; ++r) {
            float4 a = f0[r], b = f1[r], c = f2[r];
            float4 v;
            v.x = w0 * a.x + w1 * b.x + w2 * c.x;
            v.y = w0 * a.y + w1 * b.y + w2 * c.y;
            v.z = w0 * a.z + w1 * b.z + w2 * c.z;
            v.w = w0 * a.w + w1 * b.w + w2 * c.w;
            o[r] = v;
        }
    }
}

extern "C" void kernel_launch(void* const* d_in, const int* in_sizes, int n_in,
                              void* d_out, int out_size, void* d_ws, size_t ws_size,
                              hipStream_t stream) {
    const float* sp   = (const float*)d_in[0];  // source_points [N,3]
    const float* feat = (const float*)d_in[1];  // source_features [N,C]
    const float* tp   = (const float*)d_in[2];  // target_points [M,3]
    float* out = (float*)d_out;                 // [M,C] fp32

    const int N = in_sizes[0] / 3;
    const int C = in_sizes[1] / N;
    const int M = in_sizes[2] / 3;

    float4* sp4 = (float4*)d_ws;  // N*16 bytes = 256 KB

    knn_preproc<<<(N + 255) / 256, 256, 0, stream>>>(sp, sp4, N);

    const int blocks = (M + 63) / 64;  // 512 blocks of 256 threads
    knn_kernel<<<blocks, 256, 0, stream>>>(sp4, feat, tp, out, N, M, C);
}

// Round 6
// 535.459 us; speedup vs baseline: 1.0636x; 1.0636x over previous
//
#include <hip/hip_runtime.h>
#include <math.h>

#define EPS 1e-8f
#define FMAXV 3.402823466e38f
#define NW 16   // waves per block = N-split ways

// Preprocess: sp4[j] = (-2x, -2y, -2z, s2), s2 = (x*x + y*y) + z*z in strict
// fp32 no-FMA (mirrors np.sum(s*s, -1)). The -2 scale is a power of two =>
// exact, commutes with rounding. DO NOT CHANGE — bit-exactness validated R5.
__global__ void knn_preproc(const float* __restrict__ sp, float4* __restrict__ sp4, int N) {
    int j = blockIdx.x * blockDim.x + threadIdx.x;
    if (j < N) {
        float x = sp[3 * j + 0], y = sp[3 * j + 1], z = sp[3 * j + 2];
        float s2 = __fadd_rn(__fadd_rn(__fmul_rn(x, x), __fmul_rn(y, y)), __fmul_rn(z, z));
        sp4[j] = make_float4(-2.f * x, -2.f * y, -2.f * z, s2);
    }
}

__device__ __forceinline__ void insert3(float d, int j,
                                        float& d0, float& d1, float& d2,
                                        int& i0, int& i1, int& i2) {
    if (d < d2) {
        if (d < d1) {
            d2 = d1; i2 = i1;
            if (d < d0) { d1 = d0; i1 = i0; d0 = d; i0 = j; }
            else        { d1 = d;  i1 = j; }
        } else { d2 = d; i2 = j; }
    }
}

// Score mirrors the BLAS-sgemm expanded form BIT-EXACTLY (validated R5):
//   a = -2*cross via FMA chain, k ascending:  fma(z, fma(y, rn(x)))
//   d = rn(rn(t2 + a) + s2)
#define SCORE_INSERT(p, jv) do {                                          \
    float _a = fmaf((p).z, tz, fmaf((p).y, ty, __fmul_rn((p).x, tx)));    \
    float _d = __fadd_rn(__fadd_rn(t2, _a), (p).w);                       \
    insert3(_d, (jv), d0, d1, d2, i0, i1, i2);                            \
} while (0)

// One block = 64 targets (lane = target), NW=16 waves each scan a disjoint
// N/16 chunk (wave-uniform index -> scalar loads, batched 8-deep for ILP),
// merge 16 partial top-3s in LDS, IDW weights, float4 feature interpolation.
// 1024 threads, 2 blocks/CU -> 32 waves/CU (8/SIMD) to hide L2 latency.
__global__ __launch_bounds__(1024, 8) void knn_kernel(
    const float4* __restrict__ sp4, const float* __restrict__ feat,
    const float* __restrict__ tp, float* __restrict__ out,
    int N, int M, int C) {
    __shared__ float s_d[NW][3][64];   // [wave][k][lane]: lane stride 1, no conflicts
    __shared__ int   s_i[NW][3][64];
    __shared__ float s_w[3][64];
    __shared__ int   s_j[3][64];

    const int tid  = threadIdx.x;
    const int lane = tid & 63;
    const int wave = __builtin_amdgcn_readfirstlane(tid >> 6);
    const int mbase = blockIdx.x * 64;
    const int m = mbase + lane;

    float tx = 0.f, ty = 0.f, tz = 0.f;
    if (m < M) { tx = tp[3 * m + 0]; ty = tp[3 * m + 1]; tz = tp[3 * m + 2]; }
    // t2 = (tx*tx + ty*ty) + tz*tz, strict no-FMA (validated R5)
    const float t2 = __fadd_rn(__fadd_rn(__fmul_rn(tx, tx), __fmul_rn(ty, ty)),
                               __fmul_rn(tz, tz));

    float d0 = FMAXV, d1 = FMAXV, d2 = FMAXV;
    int   i0 = 0,     i1 = 0,     i2 = 0;

    const int chunk = (N + NW - 1) / NW;
    const int jbeg = wave * chunk;
    const int jend = min(jbeg + chunk, N);

    // 8-deep manual batch: 8 independent loads in flight before any use.
    int j = jbeg;
    for (; j + 8 <= jend; j += 8) {
        float4 p0 = sp4[j + 0], p1 = sp4[j + 1], p2 = sp4[j + 2], p3 = sp4[j + 3];
        float4 p4 = sp4[j + 4], p5 = sp4[j + 5], p6 = sp4[j + 6], p7 = sp4[j + 7];
        SCORE_INSERT(p0, j + 0); SCORE_INSERT(p1, j + 1);
        SCORE_INSERT(p2, j + 2); SCORE_INSERT(p3, j + 3);
        SCORE_INSERT(p4, j + 4); SCORE_INSERT(p5, j + 5);
        SCORE_INSERT(p6, j + 6); SCORE_INSERT(p7, j + 7);
    }
    for (; j < jend; ++j) { float4 p = sp4[j]; SCORE_INSERT(p, j); }

    s_d[wave][0][lane] = d0; s_d[wave][1][lane] = d1; s_d[wave][2][lane] = d2;
    s_i[wave][0][lane] = i0; s_i[wave][1][lane] = i1; s_i[wave][2][lane] = i2;
    __syncthreads();

    if (wave == 0) {
        float b0 = FMAXV, b1 = FMAXV, b2 = FMAXV;
        int   j0 = 0,     j1 = 0,     j2 = 0;
        // Merge in wave order (ascending source index) with strict '<' so
        // equal scores keep the smallest index (top_k tie-break). DO NOT
        // reorder — validated R5.
        #pragma unroll
        for (int w = 0; w < NW; ++w)
            #pragma unroll
            for (int k = 0; k < 3; ++k)
                insert3(s_d[w][k][lane], s_i[w][k][lane], b0, b1, b2, j0, j1, j2);
        // Mirror: w = 1/(d+eps); w /= (w0+w1)+w2   (all fp32, rn)
        float w0 = __fdiv_rn(1.f, __fadd_rn(b0, EPS));
        float w1 = __fdiv_rn(1.f, __fadd_rn(b1, EPS));
        float w2 = __fdiv_rn(1.f, __fadd_rn(b2, EPS));
        float sum = __fadd_rn(__fadd_rn(w0, w1), w2);
        s_w[0][lane] = __fdiv_rn(w0, sum);
        s_w[1][lane] = __fdiv_rn(w1, sum);
        s_w[2][lane] = __fdiv_rn(w2, sum);
        s_j[0][lane] = j0; s_j[1][lane] = j1; s_j[2][lane] = j2;
    }
    __syncthreads();

    // Interpolation: 16 threads per target; thread -> (tm = tid>>4, q = tid&15),
    // each handles C/64 float4s (C=128 -> 2). Consecutive tids cover a feature
    // row contiguously -> coalesced.
    const int tm = tid >> 4;
    const int q  = tid & 15;
    const int gm = mbase + tm;
    if (gm < M) {
        const int nv = C >> 6;          // float4s per 1/16 slice
        const float w0 = s_w[0][tm], w1 = s_w[1][tm], w2 = s_w[2][tm];
        const float4* f0 = (const float4*)(feat + (size_t)s_j[0][tm] * C) + q * nv;
        const float4* f1 = (const float4*)(feat + (size_t)s_j[1][tm] * C) + q * nv;
        const float4* f2 = (const float4*)(feat + (size_t)s_j[2][tm] * C) + q * nv;
        float4* o = (float4*)(out + (size_t)gm * C) + q * nv;
        for (int r = 0; r < nv; ++r) {
            float4 a = f0[r], b = f1[r], c = f2[r];
            float4 v;
            v.x = w0 * a.x + w1 * b.x + w2 * c.x;
            v.y = w0 * a.y + w1 * b.y + w2 * c.y;
            v.z = w0 * a.z + w1 * b.z + w2 * c.z;
            v.w = w0 * a.w + w1 * b.w + w2 * c.w;
            o[r] = v;
        }
    }
}

extern "C" void kernel_launch(void* const* d_in, const int* in_sizes, int n_in,
                              void* d_out, int out_size, void* d_ws, size_t ws_size,
                              hipStream_t stream) {
    const float* sp   = (const float*)d_in[0];  // source_points [N,3]
    const float* feat = (const float*)d_in[1];  // source_features [N,C]
    const float* tp   = (const float*)d_in[2];  // target_points [M,3]
    float* out = (float*)d_out;                 // [M,C] fp32

    const int N = in_sizes[0] / 3;
    const int C = in_sizes[1] / N;
    const int M = in_sizes[2] / 3;

    float4* sp4 = (float4*)d_ws;  // N*16 bytes = 256 KB

    knn_preproc<<<(N + 255) / 256, 256, 0, stream>>>(sp, sp4, N);

    const int blocks = (M + 63) / 64;  // 512 blocks of 1024 threads
    knn_kernel<<<blocks, 1024, 0, stream>>>(sp4, feat, tp, out, N, M, C);
}

// Round 7
// 176.641 us; speedup vs baseline: 3.2240x; 3.0313x over previous
//
#include <hip/hip_runtime.h>
#include <math.h>

#define EPS 1e-8f
#define FMAXV 3.402823466e38f
#define NW 16   // waves per block = N-split ways

// Preprocess: sp4[j] = (-2x, -2y, -2z, s2), s2 = (x*x + y*y) + z*z in strict
// fp32 no-FMA (mirrors np.sum(s*s, -1)). The -2 scale is a power of two =>
// exact, commutes with rounding. DO NOT CHANGE — bit-exactness validated R5.
__global__ void knn_preproc(const float* __restrict__ sp, float4* __restrict__ sp4, int N) {
    int j = blockIdx.x * blockDim.x + threadIdx.x;
    if (j < N) {
        float x = sp[3 * j + 0], y = sp[3 * j + 1], z = sp[3 * j + 2];
        float s2 = __fadd_rn(__fadd_rn(__fmul_rn(x, x), __fmul_rn(y, y)), __fmul_rn(z, z));
        sp4[j] = make_float4(-2.f * x, -2.f * y, -2.f * z, s2);
    }
}

// BRANCHLESS sorted top-3 insert. Exactly the same state transition as the
// nested-branch version (strict '<': ties keep the earlier/lower index):
//   d >= d2            -> unchanged
//   d2 > d >= d1       -> slot2 = (d,j)
//   d1 > d >= d0       -> shift slot1->2, slot1 = (d,j)
//   d  < d0            -> shift 0->1->2,  slot0 = (d,j)
// 3 v_cmp + 10 v_cndmask, no divergent branches, no saveexec/SALU traffic.
__device__ __forceinline__ void insert3_bl(float d, int j,
                                           float& d0, float& d1, float& d2,
                                           int& i0, int& i1, int& i2) {
    const bool c0 = d < d0, c1 = d < d1, c2 = d < d2;
    const float nd2 = c1 ? d1 : (c2 ? d : d2);
    const int   ni2 = c1 ? i1 : (c2 ? j : i2);
    const float nd1 = c0 ? d0 : (c1 ? d : d1);
    const int   ni1 = c0 ? i0 : (c1 ? j : i1);
    const float nd0 = c0 ? d : d0;
    const int   ni0 = c0 ? j : i0;
    d0 = nd0; d1 = nd1; d2 = nd2;
    i0 = ni0; i1 = ni1; i2 = ni2;
}

// Score mirrors the BLAS-sgemm expanded form BIT-EXACTLY (validated R5):
//   a = -2*cross via FMA chain, k ascending:  fma(z, fma(y, rn(x)))
//   d = rn(rn(t2 + a) + s2)
// Wave-uniform __any skip: one s_cbranch_vccz around the straight-line
// branchless insert — no per-lane divergence machinery.
#define SCORE_INSERT(p, jv) do {                                          \
    float _a = fmaf((p).z, tz, fmaf((p).y, ty, __fmul_rn((p).x, tx)));    \
    float _d = __fadd_rn(__fadd_rn(t2, _a), (p).w);                       \
    if (__any(_d < d2))                                                   \
        insert3_bl(_d, (jv), d0, d1, d2, i0, i1, i2);                     \
} while (0)

// One block = 64 targets (lane = target), NW=16 waves each scan a disjoint
// N/16 chunk (wave-uniform index -> scalar loads, batched 8-deep for ILP),
// merge 16 partial top-3s in LDS, IDW weights, float4 feature interpolation.
__global__ __launch_bounds__(1024, 8) void knn_kernel(
    const float4* __restrict__ sp4, const float* __restrict__ feat,
    const float* __restrict__ tp, float* __restrict__ out,
    int N, int M, int C) {
    __shared__ float s_d[NW][3][64];   // [wave][k][lane]: lane stride 1, no conflicts
    __shared__ int   s_i[NW][3][64];
    __shared__ float s_w[3][64];
    __shared__ int   s_j[3][64];

    const int tid  = threadIdx.x;
    const int lane = tid & 63;
    const int wave = __builtin_amdgcn_readfirstlane(tid >> 6);
    const int mbase = blockIdx.x * 64;
    const int m = mbase + lane;

    float tx = 0.f, ty = 0.f, tz = 0.f;
    if (m < M) { tx = tp[3 * m + 0]; ty = tp[3 * m + 1]; tz = tp[3 * m + 2]; }
    // t2 = (tx*tx + ty*ty) + tz*tz, strict no-FMA (validated R5)
    const float t2 = __fadd_rn(__fadd_rn(__fmul_rn(tx, tx), __fmul_rn(ty, ty)),
                               __fmul_rn(tz, tz));

    float d0 = FMAXV, d1 = FMAXV, d2 = FMAXV;
    int   i0 = 0,     i1 = 0,     i2 = 0;

    const int chunk = (N + NW - 1) / NW;
    const int jbeg = wave * chunk;
    const int jend = min(jbeg + chunk, N);

    // 8-deep manual batch: 8 independent loads in flight before any use.
    int j = jbeg;
    for (; j + 8 <= jend; j += 8) {
        float4 p0 = sp4[j + 0], p1 = sp4[j + 1], p2 = sp4[j + 2], p3 = sp4[j + 3];
        float4 p4 = sp4[j + 4], p5 = sp4[j + 5], p6 = sp4[j + 6], p7 = sp4[j + 7];
        SCORE_INSERT(p0, j + 0); SCORE_INSERT(p1, j + 1);
        SCORE_INSERT(p2, j + 2); SCORE_INSERT(p3, j + 3);
        SCORE_INSERT(p4, j + 4); SCORE_INSERT(p5, j + 5);
        SCORE_INSERT(p6, j + 6); SCORE_INSERT(p7, j + 7);
    }
    for (; j < jend; ++j) { float4 p = sp4[j]; SCORE_INSERT(p, j); }

    s_d[wave][0][lane] = d0; s_d[wave][1][lane] = d1; s_d[wave][2][lane] = d2;
    s_i[wave][0][lane] = i0; s_i[wave][1][lane] = i1; s_i[wave][2][lane] = i2;
    __syncthreads();

    if (wave == 0) {
        float b0 = FMAXV, b1 = FMAXV, b2 = FMAXV;
        int   j0 = 0,     j1 = 0,     j2 = 0;
        // Merge in wave order (ascending source index) with strict '<' so
        // equal scores keep the smallest index (top_k tie-break). DO NOT
        // reorder — validated R5.
        #pragma unroll
        for (int w = 0; w < NW; ++w)
            #pragma unroll
            for (int k = 0; k < 3; ++k)
                insert3_bl(s_d[w][k][lane], s_i[w][k][lane], b0, b1, b2, j0, j1, j2);
        // Mirror: w = 1/(d+eps); w /= (w0+w1)+w2   (all fp32, rn)
        float w0 = __fdiv_rn(1.f, __fadd_rn(b0, EPS));
        float w1 = __fdiv_rn(1.f, __fadd_rn(b1, EPS));
        float w2 = __fdiv_rn(1.f, __fadd_rn(b2, EPS));
        float sum = __fadd_rn(__fadd_rn(w0, w1), w2);
        s_w[0][lane] = __fdiv_rn(w0, sum);
        s_w[1][lane] = __fdiv_rn(w1, sum);
        s_w[2][lane] = __fdiv_rn(w2, sum);
        s_j[0][lane] = j0; s_j[1][lane] = j1; s_j[2][lane] = j2;
    }
    __syncthreads();

    // Interpolation: 16 threads per target; thread -> (tm = tid>>4, q = tid&15),
    // each handles C/64 float4s (C=128 -> 2). Coalesced row-contiguous access.
    const int tm = tid >> 4;
    const int q  = tid & 15;
    const int gm = mbase + tm;
    if (gm < M) {
        const int nv = C >> 6;          // float4s per 1/16 slice
        const float w0 = s_w[0][tm], w1 = s_w[1][tm], w2 = s_w[2][tm];
        const float4* f0 = (const float4*)(feat + (size_t)s_j[0][tm] * C) + q * nv;
        const float4* f1 = (const float4*)(feat + (size_t)s_j[1][tm] * C) + q * nv;
        const float4* f2 = (const float4*)(feat + (size_t)s_j[2][tm] * C) + q * nv;
        float4* o = (float4*)(out + (size_t)gm * C) + q * nv;
        for (int r = 0; r < nv; ++r) {
            float4 a = f0[r], b = f1[r], c = f2[r];
            float4 v;
            v.x = w0 * a.x + w1 * b.x + w2 * c.x;
            v.y = w0 * a.y + w1 * b.y + w2 * c.y;
            v.z = w0 * a.z + w1 * b.z + w2 * c.z;
            v.w = w0 * a.w + w1 * b.w + w2 * c.w;
            o[r] = v;
        }
    }
}

extern "C" void kernel_launch(void* const* d_in, const int* in_sizes, int n_in,
                              void* d_out, int out_size, void* d_ws, size_t ws_size,
                              hipStream_t stream) {
    const float* sp   = (const float*)d_in[0];  // source_points [N,3]
    const float* feat = (const float*)d_in[1];  // source_features [N,C]
    const float* tp   = (const float*)d_in[2];  // target_points [M,3]
    float* out = (float*)d_out;                 // [M,C] fp32

    const int N = in_sizes[0] / 3;
    const int C = in_sizes[1] / N;
    const int M = in_sizes[2] / 3;

    float4* sp4 = (float4*)d_ws;  // N*16 bytes = 256 KB

    knn_preproc<<<(N + 255) / 256, 256, 0, stream>>>(sp, sp4, N);

    const int blocks = (M + 63) / 64;  // 512 blocks of 1024 threads
    knn_kernel<<<blocks, 1024, 0, stream>>>(sp4, feat, tp, out, N, M, C);
}